// Round 6
// baseline (1172.923 us; speedup 1.0000x reference)
//
#include <hip/hip_runtime.h>

#define S_ 2048
#define C_ 128
#define B_ 4
#define H_ 8
#define D_ 64

typedef __attribute__((ext_vector_type(8))) short bf16x8;
typedef __attribute__((ext_vector_type(4))) float f32x4;

__device__ inline unsigned short f2bf(float f) {
    union { float f; unsigned int u; } c; c.f = f;
    unsigned int u = c.u;
    unsigned int r = (u + 0x7FFFu + ((u >> 16) & 1u)) >> 16;
    return (unsigned short)r;
}
__device__ inline float bf2f(unsigned short s) {
    union { unsigned int u; float f; } c; c.u = ((unsigned int)s) << 16;
    return c.f;
}

// ---------------- prep: x->bf16, weights -> packed bf16, w1 -> w1T ----------------
__global__ __launch_bounds__(256) void prep_kernel(
    const float* __restrict__ x,
    const float* __restrict__ wq, const float* __restrict__ wk,
    const float* __restrict__ wv, const float* __restrict__ w1,
    unsigned short* __restrict__ xh,
    unsigned short* __restrict__ wPackQ, unsigned short* __restrict__ wPackK,
    unsigned short* __restrict__ wPackV, float* __restrict__ w1T)
{
    int idx = blockIdx.x * 256 + threadIdx.x;
    if (idx < 1048576) {
        xh[idx] = f2bf(x[idx]);
    } else if (idx < 1245184) {               // wPackQ: i = t*65536 + o*128 + c
        int i = idx - 1048576;
        int t = i >> 16, r = i & 65535;
        int o = r >> 7, c = r & 127;
        wPackQ[i] = f2bf(wq[o * 384 + c * 3 + t]);
    } else if (idx < 1441792) {
        int i = idx - 1245184;
        int t = i >> 16, r = i & 65535;
        int o = r >> 7, c = r & 127;
        wPackK[i] = f2bf(wk[o * 384 + c * 3 + t]);
    } else if (idx < 1507328) {
        int i = idx - 1441792;
        wPackV[i] = f2bf(wv[i]);
    } else if (idx < 1540096) {
        int i = idx - 1507328;
        int j = i >> 6, d = i & 63;
        w1T[i] = w1[d * 512 + j];
    }
}

// ---------------- QKV projection via bf16 MFMA (Q,K,V fused per block) ----------------
// grid (16 s-tiles, 8 h, 4 b), block 256 (4 waves). x tile staged ONCE per block.
__global__ __launch_bounds__(256) void qkv_kernel(
    const unsigned short* __restrict__ xh,
    const unsigned short* __restrict__ wPackQ, const unsigned short* __restrict__ wPackK,
    const unsigned short* __restrict__ wPackV,
    const float* __restrict__ bq, const float* __restrict__ bk,
    const float* __restrict__ bv,
    unsigned short* __restrict__ Qh, unsigned short* __restrict__ Kh,
    unsigned short* __restrict__ VhT)
{
    __shared__ __align__(16) short xs[130 * 136];
    __shared__ __align__(16) short ws[64 * 136];

    int s0 = blockIdx.x * 128;
    int h = blockIdx.y;
    int b = blockIdx.z;
    int bh = b * H_ + h;
    int tid = threadIdx.x;
    int w = tid >> 6;
    int lane = tid & 63;
    int col = lane & 15;
    int quad = lane >> 4;

    // stage x tile (130 rows x 128 c) once
    for (int i = tid; i < 2080; i += 256) {
        int row = i >> 4, c8 = (i & 15) << 3;
        int s = s0 - 2 + row;
        uint4 v = {0u, 0u, 0u, 0u};
        if (s >= 0) v = *(const uint4*)&xh[((long)b * S_ + s) * C_ + c8];
        *(uint4*)&xs[row * 136 + c8] = v;
    }

    for (int sec = 0; sec < 3; sec++) {
        const unsigned short* wsel = (sec == 0) ? wPackQ : (sec == 1) ? wPackK : wPackV;
        int tlo = (sec == 2) ? 2 : 0;

        f32x4 acc[2][4];
        #pragma unroll
        for (int rt = 0; rt < 2; rt++)
            #pragma unroll
            for (int nt = 0; nt < 4; nt++) acc[rt][nt] = (f32x4){0.f, 0.f, 0.f, 0.f};

        for (int t = tlo; t < 3; t++) {
            if (!(sec == 0 && t == 0)) __syncthreads();   // prev ws readers done
            long wbase = (sec == 2) ? ((long)h * 8192)
                                    : ((long)t * 65536 + (long)h * 8192);
            for (int i = tid; i < 1024; i += 256) {
                int row = i >> 4, c8 = (i & 15) << 3;
                *(uint4*)&ws[row * 136 + c8] = *(const uint4*)&wsel[wbase + row * 128 + c8];
            }
            __syncthreads();                              // ws (and xs, first time) visible

            #pragma unroll
            for (int kc = 0; kc < 4; kc++) {
                int ko = kc * 32 + quad * 8;
                bf16x8 a0 = *(const bf16x8*)&xs[(w * 32 + col + t) * 136 + ko];
                bf16x8 a1 = *(const bf16x8*)&xs[(w * 32 + 16 + col + t) * 136 + ko];
                #pragma unroll
                for (int nt = 0; nt < 4; nt++) {
                    bf16x8 bfr = *(const bf16x8*)&ws[(nt * 16 + col) * 136 + ko];
                    acc[0][nt] = __builtin_amdgcn_mfma_f32_16x16x32_bf16(a0, bfr, acc[0][nt], 0, 0, 0);
                    acc[1][nt] = __builtin_amdgcn_mfma_f32_16x16x32_bf16(a1, bfr, acc[1][nt], 0, 0, 0);
                }
            }
        }

        if (sec == 0) {               // Q: (acc+bias)*0.125
            #pragma unroll
            for (int nt = 0; nt < 4; nt++) {
                float bias = bq[h * 64 + nt * 16 + col];
                #pragma unroll
                for (int rt = 0; rt < 2; rt++)
                    #pragma unroll
                    for (int r = 0; r < 4; r++) {
                        int s = s0 + w * 32 + rt * 16 + quad * 4 + r;
                        Qh[((long)bh * S_ + s) * D_ + nt * 16 + col] =
                            f2bf((acc[rt][nt][r] + bias) * 0.125f);
                    }
            }
        } else if (sec == 1) {        // K
            #pragma unroll
            for (int nt = 0; nt < 4; nt++) {
                float bias = bk[h * 64 + nt * 16 + col];
                #pragma unroll
                for (int rt = 0; rt < 2; rt++)
                    #pragma unroll
                    for (int r = 0; r < 4; r++) {
                        int s = s0 + w * 32 + rt * 16 + quad * 4 + r;
                        Kh[((long)bh * S_ + s) * D_ + nt * 16 + col] =
                            f2bf(acc[rt][nt][r] + bias);
                    }
            }
        } else {                      // V: relu -> transpose via ws -> VhT[bh][d][s]
            __syncthreads();          // all MFMA reads of ws done
            #pragma unroll
            for (int nt = 0; nt < 4; nt++) {
                float bias = bv[h * 64 + nt * 16 + col];
                #pragma unroll
                for (int rt = 0; rt < 2; rt++)
                    #pragma unroll
                    for (int r = 0; r < 4; r++) {
                        int sl = w * 32 + rt * 16 + quad * 4 + r;
                        ws[(nt * 16 + col) * 136 + sl] =
                            (short)f2bf(fmaxf(acc[rt][nt][r] + bias, 0.f));
                    }
            }
            __syncthreads();
            for (int i = tid; i < 1024; i += 256) {
                int row = i >> 4, c8 = (i & 15) << 3;
                *(uint4*)&VhT[((long)bh * D_ + row) * S_ + s0 + c8] =
                    *(const uint4*)&ws[row * 136 + c8];
            }
        }
    }
}

// ---------------- fused flash attention ----------------
// 1-D grid 1024. xcd = idx&7 pins bh group to one XCD L2. qt remap
// (t<16 ? t : 47-t) makes every CU's 4 co-resident blocks sum to 66 work
// units (was 52..80) AND gives all 4 the same bh (L1 reuse).
__global__ __launch_bounds__(256) void attn_kernel(
    const unsigned short* __restrict__ Qh, const unsigned short* __restrict__ Kh,
    const unsigned short* __restrict__ VhT, const int* __restrict__ length,
    float* __restrict__ score, float* __restrict__ out2)
{
    __shared__ __align__(16) short Kbuf[2][64 * 72];  // pass1: K dbuf; pass2: [0]=K,[1]=V^T
    __shared__ __align__(16) short Pfh[64 * 76];      // Q tile, then P bf16 [q][k] (stride 76)

    int idx = blockIdx.x;
    int xcd = idx & 7;
    int slot = idx >> 3;
    int t = slot >> 2;
    int qt = (t < 16) ? t : 47 - t;
    int bh = xcd * 4 + (slot & 3);
    int b = bh >> 3, h = bh & 7;
    int q0 = qt * 64;
    int tid = threadIdx.x;
    int w = tid >> 6;
    int lane = tid & 63;
    int col = lane & 15;
    int quad = lane >> 4;
    int len = length[b];

    const unsigned short* Qb = Qh + (long)bh * S_ * D_;
    const unsigned short* Kb = Kh + (long)bh * S_ * D_;
    const unsigned short* Vtb = VhT + (long)bh * D_ * S_;
    float* scb = score + (long)bh * S_ * S_;

    int srow_ = tid >> 2, sc16_ = (tid & 3) * 16;   // staging coords

    {   // stage Q tile into Pfh region (stride 76)
        *(uint4*)&Pfh[srow_ * 76 + sc16_]     = *(const uint4*)&Qb[(q0 + srow_) * D_ + sc16_];
        *(uint4*)&Pfh[srow_ * 76 + sc16_ + 8] = *(const uint4*)&Qb[(q0 + srow_) * D_ + sc16_ + 8];
    }
    __syncthreads();
    int arow = w * 16 + col;
    bf16x8 aq0 = *(const bf16x8*)&Pfh[arow * 76 + quad * 8];
    bf16x8 aq1 = *(const bf16x8*)&Pfh[arow * 76 + 32 + quad * 8];

    // ---- pass 1: l = sum(exp(s)) per row, K double-buffered (1 barrier/iter) ----
    float lrun[4];
    #pragma unroll
    for (int r = 0; r < 4; r++) lrun[r] = 0.f;

    {   // prologue: stage K tile 0
        *(uint4*)&Kbuf[0][srow_ * 72 + sc16_]     = *(const uint4*)&Kb[srow_ * D_ + sc16_];
        *(uint4*)&Kbuf[0][srow_ * 72 + sc16_ + 8] = *(const uint4*)&Kb[srow_ * D_ + sc16_ + 8];
    }
    __syncthreads();

    for (int kt = 0; kt <= qt; kt++) {
        int buf = kt & 1;
        if (kt < qt) {   // prefetch next K tile into the other buffer
            *(uint4*)&Kbuf[1 - buf][srow_ * 72 + sc16_] =
                *(const uint4*)&Kb[((kt + 1) * 64 + srow_) * D_ + sc16_];
            *(uint4*)&Kbuf[1 - buf][srow_ * 72 + sc16_ + 8] =
                *(const uint4*)&Kb[((kt + 1) * 64 + srow_) * D_ + sc16_ + 8];
        }

        f32x4 acc[4];
        #pragma unroll
        for (int n = 0; n < 4; n++) acc[n] = (f32x4){0.f, 0.f, 0.f, 0.f};
        #pragma unroll
        for (int n = 0; n < 4; n++) {
            bf16x8 b0 = *(const bf16x8*)&Kbuf[buf][(n * 16 + col) * 72 + quad * 8];
            acc[n] = __builtin_amdgcn_mfma_f32_16x16x32_bf16(aq0, b0, acc[n], 0, 0, 0);
            bf16x8 b1 = *(const bf16x8*)&Kbuf[buf][(n * 16 + col) * 72 + 32 + quad * 8];
            acc[n] = __builtin_amdgcn_mfma_f32_16x16x32_bf16(aq1, b1, acc[n], 0, 0, 0);
        }
        if (kt == qt) {
            #pragma unroll
            for (int n = 0; n < 4; n++) {
                int kk = kt * 64 + n * 16 + col;
                #pragma unroll
                for (int r = 0; r < 4; r++) {
                    int q = q0 + w * 16 + quad * 4 + r;
                    if (kk > q) acc[n][r] = -1.0e30f;
                }
            }
        }
        #pragma unroll
        for (int r = 0; r < 4; r++) {
            lrun[r] += __expf(acc[0][r]) + __expf(acc[1][r]) +
                       __expf(acc[2][r]) + __expf(acc[3][r]);
        }
        __syncthreads();   // prefetch visible + buf readers done before overwrite
    }

    #pragma unroll
    for (int off = 1; off < 16; off <<= 1) {
        #pragma unroll
        for (int r = 0; r < 4; r++) lrun[r] += __shfl_xor(lrun[r], off, 64);
    }
    float linv[4];
    #pragma unroll
    for (int r = 0; r < 4; r++) linv[r] = 1.0f / lrun[r];

    // ---- pass 2: recompute logits, bf16 P (wave-local LDS), NT score store, P@V ----
    f32x4 oacc[4];
    #pragma unroll
    for (int n = 0; n < 4; n++) oacc[n] = (f32x4){0.f, 0.f, 0.f, 0.f};

    for (int kt = 0; kt <= qt; kt++) {
        __syncthreads();   // Kbuf readers of previous iter done
        {
            *(uint4*)&Kbuf[0][srow_ * 72 + sc16_] =
                *(const uint4*)&Kb[(kt * 64 + srow_) * D_ + sc16_];
            *(uint4*)&Kbuf[0][srow_ * 72 + sc16_ + 8] =
                *(const uint4*)&Kb[(kt * 64 + srow_) * D_ + sc16_ + 8];
            *(uint4*)&Kbuf[1][srow_ * 72 + sc16_] =
                *(const uint4*)&Vtb[srow_ * S_ + kt * 64 + sc16_];
            *(uint4*)&Kbuf[1][srow_ * 72 + sc16_ + 8] =
                *(const uint4*)&Vtb[srow_ * S_ + kt * 64 + sc16_ + 8];
        }
        __syncthreads();

        f32x4 acc[4];
        #pragma unroll
        for (int n = 0; n < 4; n++) acc[n] = (f32x4){0.f, 0.f, 0.f, 0.f};
        #pragma unroll
        for (int n = 0; n < 4; n++) {
            bf16x8 b0 = *(const bf16x8*)&Kbuf[0][(n * 16 + col) * 72 + quad * 8];
            acc[n] = __builtin_amdgcn_mfma_f32_16x16x32_bf16(aq0, b0, acc[n], 0, 0, 0);
            bf16x8 b1 = *(const bf16x8*)&Kbuf[0][(n * 16 + col) * 72 + 32 + quad * 8];
            acc[n] = __builtin_amdgcn_mfma_f32_16x16x32_bf16(aq1, b1, acc[n], 0, 0, 0);
        }

        bool diag = (kt == qt);
        #pragma unroll
        for (int n = 0; n < 4; n++) {
            int kk = kt * 64 + n * 16 + col;
            #pragma unroll
            for (int r = 0; r < 4; r++) {
                int q = q0 + w * 16 + quad * 4 + r;
                float p = __expf(acc[n][r]) * linv[r];
                if (q >= len || (diag && kk > q)) p = 0.f;
                Pfh[(w * 16 + quad * 4 + r) * 76 + n * 16 + col] = (short)f2bf(p);
            }
        }
        // P bf16 [q][k] -> A-fragments (wave-local rows, no barrier needed)
        bf16x8 pa0 = *(const bf16x8*)&Pfh[(w * 16 + col) * 76 + quad * 8];
        bf16x8 pa1 = *(const bf16x8*)&Pfh[(w * 16 + col) * 76 + 32 + quad * 8];
        #pragma unroll
        for (int n = 0; n < 4; n++) {
            bf16x8 v0 = *(const bf16x8*)&Kbuf[1][(n * 16 + col) * 72 + quad * 8];
            oacc[n] = __builtin_amdgcn_mfma_f32_16x16x32_bf16(pa0, v0, oacc[n], 0, 0, 0);
            bf16x8 v1 = *(const bf16x8*)&Kbuf[1][(n * 16 + col) * 72 + 32 + quad * 8];
            oacc[n] = __builtin_amdgcn_mfma_f32_16x16x32_bf16(pa1, v1, oacc[n], 0, 0, 0);
        }

        // wave-local coop score store: wave w owns rows w*16..w*16+15 of Pfh
        {
            int row = w * 16 + (lane >> 2);
            int c16 = (lane & 3) * 16;
            #pragma unroll
            for (int j = 0; j < 4; j++) {
                uint2 pk = *(const uint2*)&Pfh[row * 76 + c16 + j * 4];
                f32x4 v;
                v[0] = bf2f((unsigned short)(pk.x & 0xFFFFu));
                v[1] = bf2f((unsigned short)(pk.x >> 16));
                v[2] = bf2f((unsigned short)(pk.y & 0xFFFFu));
                v[3] = bf2f((unsigned short)(pk.y >> 16));
                __builtin_nontemporal_store(v,
                    (f32x4*)&scb[(long)(q0 + row) * S_ + kt * 64 + c16 + j * 4]);
            }
        }
    }

    // out2[b][s][h*64+dv]
    #pragma unroll
    for (int n = 0; n < 4; n++) {
        #pragma unroll
        for (int r = 0; r < 4; r++) {
            int q = q0 + w * 16 + quad * 4 + r;
            out2[((long)(b * S_ + q)) * 512 + h * 64 + n * 16 + col] = oacc[n][r];
        }
    }

    // zero the strictly-above-diagonal tiles (NT streaming)
    f32x4 z = (f32x4){0.f, 0.f, 0.f, 0.f};
    for (int kt2 = qt + 1; kt2 < 32; kt2++) {
        #pragma unroll
        for (int it = 0; it < 4; it++) {
            int idx2 = tid + it * 256;
            int rr = idx2 >> 4, cc = idx2 & 15;
            __builtin_nontemporal_store(z,
                (f32x4*)&scb[(long)(q0 + rr) * S_ + kt2 * 64 + cc * 4]);
        }
    }
}

// ---------------- MLP head ----------------
__global__ __launch_bounds__(256) void mlp_kernel(
    const float* __restrict__ out2, const float* __restrict__ w1T,
    const float* __restrict__ b1, const float* __restrict__ w2,
    const float* __restrict__ b2, float* __restrict__ out3)
{
    __shared__ float xr[2048];
    int sg0 = blockIdx.x * 4;
    int tid = threadIdx.x;
    for (int i = tid; i < 2048; i += 256) xr[i] = out2[(long)sg0 * 512 + i];
    __syncthreads();

    int sl = tid >> 6, d = tid & 63;
    float acc = 0.f;
    const float* xp = &xr[sl * 512];
    #pragma unroll 8
    for (int j = 0; j < 512; j++) acc += xp[j] * w1T[j * 64 + d];
    float hval = fmaxf(acc + b1[d], 0.f);
    float p = hval * w2[d];
    #pragma unroll
    for (int off = 32; off > 0; off >>= 1) p += __shfl_xor(p, off, 64);
    if (d == 0) out3[sg0 + sl] = p + b2[0];
}

// ---------------- launcher ----------------
extern "C" void kernel_launch(void* const* d_in, const int* in_sizes, int n_in,
                              void* d_out, int out_size, void* d_ws, size_t ws_size,
                              hipStream_t stream) {
    const float* x      = (const float*)d_in[0];
    const int*   length = (const int*)  d_in[1];
    const float* wq     = (const float*)d_in[2];
    const float* bq     = (const float*)d_in[3];
    const float* wk     = (const float*)d_in[4];
    const float* bk     = (const float*)d_in[5];
    const float* wv     = (const float*)d_in[6];
    const float* bv     = (const float*)d_in[7];
    const float* w1     = (const float*)d_in[8];
    const float* b1     = (const float*)d_in[9];
    const float* w2     = (const float*)d_in[10];
    const float* b2     = (const float*)d_in[11];

    float* out3  = (float*)d_out;
    float* score = (float*)d_out + 8192;   // (B,H,S,S) follows (B,S,1)

    float* ws  = (float*)d_ws;
    unsigned short* xh     = (unsigned short*)ws;  ws += 524288;
    unsigned short* wPackQ = (unsigned short*)ws;  ws += 98304;
    unsigned short* wPackK = (unsigned short*)ws;  ws += 98304;
    unsigned short* wPackV = (unsigned short*)ws;  ws += 32768;
    float* w1T = ws;  ws += 32768;
    unsigned short* Qh  = (unsigned short*)ws;  ws += 2097152;
    unsigned short* Kh  = (unsigned short*)ws;  ws += 2097152;
    unsigned short* VhT = (unsigned short*)ws;  ws += 2097152;
    float* o2  = ws;  ws += 4194304;

    hipLaunchKernelGGL(prep_kernel, dim3(6016), dim3(256), 0, stream,
                       x, wq, wk, wv, w1, xh, wPackQ, wPackK, wPackV, w1T);
    hipLaunchKernelGGL(qkv_kernel, dim3(16, 8, 4), dim3(256), 0, stream,
                       xh, wPackQ, wPackK, wPackV, bq, bk, bv, Qh, Kh, VhT);
    hipLaunchKernelGGL(attn_kernel, dim3(1024), dim3(256), 0, stream,
                       Qh, Kh, VhT, length, score, o2);
    hipLaunchKernelGGL(mlp_kernel, dim3(2048), dim3(256), 0, stream,
                       o2, w1T, b1, w2, b2, out3);
}

// Round 7
// 656.536 us; speedup vs baseline: 1.7865x; 1.7865x over previous
//
#include <hip/hip_runtime.h>

#define S_ 2048
#define C_ 128
#define B_ 4
#define H_ 8
#define D_ 64

typedef __attribute__((ext_vector_type(8))) short bf16x8;
typedef __attribute__((ext_vector_type(4))) float f32x4;

__device__ inline unsigned short f2bf(float f) {
    union { float f; unsigned int u; } c; c.f = f;
    unsigned int u = c.u;
    unsigned int r = (u + 0x7FFFu + ((u >> 16) & 1u)) >> 16;
    return (unsigned short)r;
}
__device__ inline float bf2f(unsigned short s) {
    union { unsigned int u; float f; } c; c.u = ((unsigned int)s) << 16;
    return c.f;
}

// ---------------- prep: x->bf16, weights -> packed bf16, w1 -> w1T ----------------
__global__ __launch_bounds__(256) void prep_kernel(
    const float* __restrict__ x,
    const float* __restrict__ wq, const float* __restrict__ wk,
    const float* __restrict__ wv, const float* __restrict__ w1,
    unsigned short* __restrict__ xh,
    unsigned short* __restrict__ wPackQ, unsigned short* __restrict__ wPackK,
    unsigned short* __restrict__ wPackV, float* __restrict__ w1T)
{
    int idx = blockIdx.x * 256 + threadIdx.x;
    if (idx < 1048576) {
        xh[idx] = f2bf(x[idx]);
    } else if (idx < 1245184) {               // wPackQ: i = t*65536 + o*128 + c
        int i = idx - 1048576;
        int t = i >> 16, r = i & 65535;
        int o = r >> 7, c = r & 127;
        wPackQ[i] = f2bf(wq[o * 384 + c * 3 + t]);
    } else if (idx < 1441792) {
        int i = idx - 1245184;
        int t = i >> 16, r = i & 65535;
        int o = r >> 7, c = r & 127;
        wPackK[i] = f2bf(wk[o * 384 + c * 3 + t]);
    } else if (idx < 1507328) {
        int i = idx - 1441792;
        wPackV[i] = f2bf(wv[i]);
    } else if (idx < 1540096) {
        int i = idx - 1507328;
        int j = i >> 6, d = i & 63;
        w1T[i] = w1[d * 512 + j];
    }
}

// ---------------- QKV projection via bf16 MFMA (Q,K,V fused per block) ----------------
__global__ __launch_bounds__(256) void qkv_kernel(
    const unsigned short* __restrict__ xh,
    const unsigned short* __restrict__ wPackQ, const unsigned short* __restrict__ wPackK,
    const unsigned short* __restrict__ wPackV,
    const float* __restrict__ bq, const float* __restrict__ bk,
    const float* __restrict__ bv,
    unsigned short* __restrict__ Qh, unsigned short* __restrict__ Kh,
    unsigned short* __restrict__ VhT)
{
    __shared__ __align__(16) short xs[130 * 136];
    __shared__ __align__(16) short ws[64 * 136];

    int s0 = blockIdx.x * 128;
    int h = blockIdx.y;
    int b = blockIdx.z;
    int bh = b * H_ + h;
    int tid = threadIdx.x;
    int w = tid >> 6;
    int lane = tid & 63;
    int col = lane & 15;
    int quad = lane >> 4;

    for (int i = tid; i < 2080; i += 256) {
        int row = i >> 4, c8 = (i & 15) << 3;
        int s = s0 - 2 + row;
        uint4 v = {0u, 0u, 0u, 0u};
        if (s >= 0) v = *(const uint4*)&xh[((long)b * S_ + s) * C_ + c8];
        *(uint4*)&xs[row * 136 + c8] = v;
    }

    for (int sec = 0; sec < 3; sec++) {
        const unsigned short* wsel = (sec == 0) ? wPackQ : (sec == 1) ? wPackK : wPackV;
        int tlo = (sec == 2) ? 2 : 0;

        f32x4 acc[2][4];
        #pragma unroll
        for (int rt = 0; rt < 2; rt++)
            #pragma unroll
            for (int nt = 0; nt < 4; nt++) acc[rt][nt] = (f32x4){0.f, 0.f, 0.f, 0.f};

        for (int t = tlo; t < 3; t++) {
            if (!(sec == 0 && t == 0)) __syncthreads();
            long wbase = (sec == 2) ? ((long)h * 8192)
                                    : ((long)t * 65536 + (long)h * 8192);
            for (int i = tid; i < 1024; i += 256) {
                int row = i >> 4, c8 = (i & 15) << 3;
                *(uint4*)&ws[row * 136 + c8] = *(const uint4*)&wsel[wbase + row * 128 + c8];
            }
            __syncthreads();

            #pragma unroll
            for (int kc = 0; kc < 4; kc++) {
                int ko = kc * 32 + quad * 8;
                bf16x8 a0 = *(const bf16x8*)&xs[(w * 32 + col + t) * 136 + ko];
                bf16x8 a1 = *(const bf16x8*)&xs[(w * 32 + 16 + col + t) * 136 + ko];
                #pragma unroll
                for (int nt = 0; nt < 4; nt++) {
                    bf16x8 bfr = *(const bf16x8*)&ws[(nt * 16 + col) * 136 + ko];
                    acc[0][nt] = __builtin_amdgcn_mfma_f32_16x16x32_bf16(a0, bfr, acc[0][nt], 0, 0, 0);
                    acc[1][nt] = __builtin_amdgcn_mfma_f32_16x16x32_bf16(a1, bfr, acc[1][nt], 0, 0, 0);
                }
            }
        }

        if (sec == 0) {
            #pragma unroll
            for (int nt = 0; nt < 4; nt++) {
                float bias = bq[h * 64 + nt * 16 + col];
                #pragma unroll
                for (int rt = 0; rt < 2; rt++)
                    #pragma unroll
                    for (int r = 0; r < 4; r++) {
                        int s = s0 + w * 32 + rt * 16 + quad * 4 + r;
                        Qh[((long)bh * S_ + s) * D_ + nt * 16 + col] =
                            f2bf((acc[rt][nt][r] + bias) * 0.125f);
                    }
            }
        } else if (sec == 1) {
            #pragma unroll
            for (int nt = 0; nt < 4; nt++) {
                float bias = bk[h * 64 + nt * 16 + col];
                #pragma unroll
                for (int rt = 0; rt < 2; rt++)
                    #pragma unroll
                    for (int r = 0; r < 4; r++) {
                        int s = s0 + w * 32 + rt * 16 + quad * 4 + r;
                        Kh[((long)bh * S_ + s) * D_ + nt * 16 + col] =
                            f2bf(acc[rt][nt][r] + bias);
                    }
            }
        } else {
            __syncthreads();
            #pragma unroll
            for (int nt = 0; nt < 4; nt++) {
                float bias = bv[h * 64 + nt * 16 + col];
                #pragma unroll
                for (int rt = 0; rt < 2; rt++)
                    #pragma unroll
                    for (int r = 0; r < 4; r++) {
                        int sl = w * 32 + rt * 16 + quad * 4 + r;
                        ws[(nt * 16 + col) * 136 + sl] =
                            (short)f2bf(fmaxf(acc[rt][nt][r] + bias, 0.f));
                    }
            }
            __syncthreads();
            for (int i = tid; i < 1024; i += 256) {
                int row = i >> 4, c8 = (i & 15) << 3;
                *(uint4*)&VhT[((long)bh * D_ + row) * S_ + s0 + c8] =
                    *(const uint4*)&ws[row * 136 + c8];
            }
        }
    }
}

// ---------------- fused flash attention ----------------
// 1-D grid 1024. XCD-pinned (idx&7), CU-balanced qt remap. Score store is
// wave-local but per-instruction COALESCED (full 256B row segments), NT.
#define PST 78   // Pfh stride in shorts (39 words, odd -> conflict-free-ish)
__global__ __launch_bounds__(256) void attn_kernel(
    const unsigned short* __restrict__ Qh, const unsigned short* __restrict__ Kh,
    const unsigned short* __restrict__ VhT, const int* __restrict__ length,
    float* __restrict__ score, float* __restrict__ out2)
{
    __shared__ __align__(16) short Kbuf[2][64 * 72];  // pass1: K dbuf; pass2: [0]=K,[1]=V^T
    __shared__ __align__(16) short Pfh[64 * PST];     // Q tile, then P bf16 [q][k]

    int idx = blockIdx.x;
    int xcd = idx & 7;
    int slot = idx >> 3;
    int t = slot >> 2;
    int qt = (t < 16) ? t : 47 - t;
    int bh = xcd * 4 + (slot & 3);
    int b = bh >> 3, h = bh & 7;
    int q0 = qt * 64;
    int tid = threadIdx.x;
    int w = tid >> 6;
    int lane = tid & 63;
    int col = lane & 15;
    int quad = lane >> 4;
    int len = length[b];

    const unsigned short* Qb = Qh + (long)bh * S_ * D_;
    const unsigned short* Kb = Kh + (long)bh * S_ * D_;
    const unsigned short* Vtb = VhT + (long)bh * D_ * S_;
    float* scb = score + (long)bh * S_ * S_;

    int srow_ = tid >> 2, sc16_ = (tid & 3) * 16;   // staging coords

    {   // stage Q tile into Pfh region
        *(uint4*)&Pfh[srow_ * PST + sc16_]     = *(const uint4*)&Qb[(q0 + srow_) * D_ + sc16_];
        *(uint4*)&Pfh[srow_ * PST + sc16_ + 8] = *(const uint4*)&Qb[(q0 + srow_) * D_ + sc16_ + 8];
    }
    __syncthreads();
    int arow = w * 16 + col;
    bf16x8 aq0 = *(const bf16x8*)&Pfh[arow * PST + quad * 8];
    bf16x8 aq1 = *(const bf16x8*)&Pfh[arow * PST + 32 + quad * 8];

    // ---- pass 1: l = sum(exp(s)) per row, K double-buffered ----
    float lrun[4];
    #pragma unroll
    for (int r = 0; r < 4; r++) lrun[r] = 0.f;

    {   // prologue: stage K tile 0
        *(uint4*)&Kbuf[0][srow_ * 72 + sc16_]     = *(const uint4*)&Kb[srow_ * D_ + sc16_];
        *(uint4*)&Kbuf[0][srow_ * 72 + sc16_ + 8] = *(const uint4*)&Kb[srow_ * D_ + sc16_ + 8];
    }
    __syncthreads();

    for (int kt = 0; kt <= qt; kt++) {
        int buf = kt & 1;
        if (kt < qt) {
            *(uint4*)&Kbuf[1 - buf][srow_ * 72 + sc16_] =
                *(const uint4*)&Kb[((kt + 1) * 64 + srow_) * D_ + sc16_];
            *(uint4*)&Kbuf[1 - buf][srow_ * 72 + sc16_ + 8] =
                *(const uint4*)&Kb[((kt + 1) * 64 + srow_) * D_ + sc16_ + 8];
        }

        f32x4 acc[4];
        #pragma unroll
        for (int n = 0; n < 4; n++) acc[n] = (f32x4){0.f, 0.f, 0.f, 0.f};
        #pragma unroll
        for (int n = 0; n < 4; n++) {
            bf16x8 b0 = *(const bf16x8*)&Kbuf[buf][(n * 16 + col) * 72 + quad * 8];
            acc[n] = __builtin_amdgcn_mfma_f32_16x16x32_bf16(aq0, b0, acc[n], 0, 0, 0);
            bf16x8 b1 = *(const bf16x8*)&Kbuf[buf][(n * 16 + col) * 72 + 32 + quad * 8];
            acc[n] = __builtin_amdgcn_mfma_f32_16x16x32_bf16(aq1, b1, acc[n], 0, 0, 0);
        }
        if (kt == qt) {
            #pragma unroll
            for (int n = 0; n < 4; n++) {
                int kk = kt * 64 + n * 16 + col;
                #pragma unroll
                for (int r = 0; r < 4; r++) {
                    int q = q0 + w * 16 + quad * 4 + r;
                    if (kk > q) acc[n][r] = -1.0e30f;
                }
            }
        }
        #pragma unroll
        for (int r = 0; r < 4; r++) {
            lrun[r] += __expf(acc[0][r]) + __expf(acc[1][r]) +
                       __expf(acc[2][r]) + __expf(acc[3][r]);
        }
        __syncthreads();
    }

    #pragma unroll
    for (int off = 1; off < 16; off <<= 1) {
        #pragma unroll
        for (int r = 0; r < 4; r++) lrun[r] += __shfl_xor(lrun[r], off, 64);
    }
    float linv[4];
    #pragma unroll
    for (int r = 0; r < 4; r++) linv[r] = 1.0f / lrun[r];

    // ---- pass 2: recompute logits, bf16 P (wave-local), coalesced NT store, P@V ----
    f32x4 oacc[4];
    #pragma unroll
    for (int n = 0; n < 4; n++) oacc[n] = (f32x4){0.f, 0.f, 0.f, 0.f};

    for (int kt = 0; kt <= qt; kt++) {
        __syncthreads();
        {
            *(uint4*)&Kbuf[0][srow_ * 72 + sc16_] =
                *(const uint4*)&Kb[(kt * 64 + srow_) * D_ + sc16_];
            *(uint4*)&Kbuf[0][srow_ * 72 + sc16_ + 8] =
                *(const uint4*)&Kb[(kt * 64 + srow_) * D_ + sc16_ + 8];
            *(uint4*)&Kbuf[1][srow_ * 72 + sc16_] =
                *(const uint4*)&Vtb[srow_ * S_ + kt * 64 + sc16_];
            *(uint4*)&Kbuf[1][srow_ * 72 + sc16_ + 8] =
                *(const uint4*)&Vtb[srow_ * S_ + kt * 64 + sc16_ + 8];
        }
        __syncthreads();

        f32x4 acc[4];
        #pragma unroll
        for (int n = 0; n < 4; n++) acc[n] = (f32x4){0.f, 0.f, 0.f, 0.f};
        #pragma unroll
        for (int n = 0; n < 4; n++) {
            bf16x8 b0 = *(const bf16x8*)&Kbuf[0][(n * 16 + col) * 72 + quad * 8];
            acc[n] = __builtin_amdgcn_mfma_f32_16x16x32_bf16(aq0, b0, acc[n], 0, 0, 0);
            bf16x8 b1 = *(const bf16x8*)&Kbuf[0][(n * 16 + col) * 72 + 32 + quad * 8];
            acc[n] = __builtin_amdgcn_mfma_f32_16x16x32_bf16(aq1, b1, acc[n], 0, 0, 0);
        }

        bool diag = (kt == qt);
        #pragma unroll
        for (int n = 0; n < 4; n++) {
            int kk = kt * 64 + n * 16 + col;
            #pragma unroll
            for (int r = 0; r < 4; r++) {
                int q = q0 + w * 16 + quad * 4 + r;
                float p = __expf(acc[n][r]) * linv[r];
                if (q >= len || (diag && kk > q)) p = 0.f;
                Pfh[(w * 16 + quad * 4 + r) * PST + n * 16 + col] = (short)f2bf(p);
            }
        }
        // P bf16 [q][k] -> A-fragments (wave-local rows, no barrier)
        bf16x8 pa0 = *(const bf16x8*)&Pfh[(w * 16 + col) * PST + quad * 8];
        bf16x8 pa1 = *(const bf16x8*)&Pfh[(w * 16 + col) * PST + 32 + quad * 8];
        #pragma unroll
        for (int n = 0; n < 4; n++) {
            bf16x8 v0 = *(const bf16x8*)&Kbuf[1][(n * 16 + col) * 72 + quad * 8];
            oacc[n] = __builtin_amdgcn_mfma_f32_16x16x32_bf16(pa0, v0, oacc[n], 0, 0, 0);
            bf16x8 v1 = *(const bf16x8*)&Kbuf[1][(n * 16 + col) * 72 + 32 + quad * 8];
            oacc[n] = __builtin_amdgcn_mfma_f32_16x16x32_bf16(pa1, v1, oacc[n], 0, 0, 0);
        }

        // wave-local coalesced score store: per j, 16 lanes cover one full
        // 256B row segment; 4 rows per instruction stream, 16 rows total.
        {
            int rlo = lane >> 4;          // 0..3
            int c4 = (lane & 15) * 4;     // float offset in row
            #pragma unroll
            for (int j = 0; j < 4; j++) {
                int row = w * 16 + j * 4 + rlo;
                uint2 pk = *(const uint2*)&Pfh[row * PST + c4];
                f32x4 v;
                v[0] = bf2f((unsigned short)(pk.x & 0xFFFFu));
                v[1] = bf2f((unsigned short)(pk.x >> 16));
                v[2] = bf2f((unsigned short)(pk.y & 0xFFFFu));
                v[3] = bf2f((unsigned short)(pk.y >> 16));
                __builtin_nontemporal_store(v,
                    (f32x4*)&scb[(long)(q0 + row) * S_ + kt * 64 + c4]);
            }
        }
    }

    // out2[b][s][h*64+dv]
    #pragma unroll
    for (int n = 0; n < 4; n++) {
        #pragma unroll
        for (int r = 0; r < 4; r++) {
            int q = q0 + w * 16 + quad * 4 + r;
            out2[((long)(b * S_ + q)) * 512 + h * 64 + n * 16 + col] = oacc[n][r];
        }
    }

    // zero the strictly-above-diagonal tiles (NT, coalesced)
    f32x4 z = (f32x4){0.f, 0.f, 0.f, 0.f};
    for (int kt2 = qt + 1; kt2 < 32; kt2++) {
        #pragma unroll
        for (int it = 0; it < 4; it++) {
            int idx2 = tid + it * 256;
            int rr = idx2 >> 4, cc = idx2 & 15;
            __builtin_nontemporal_store(z,
                (f32x4*)&scb[(long)(q0 + rr) * S_ + kt2 * 64 + cc * 4]);
        }
    }
}

// ---------------- MLP head ----------------
__global__ __launch_bounds__(256) void mlp_kernel(
    const float* __restrict__ out2, const float* __restrict__ w1T,
    const float* __restrict__ b1, const float* __restrict__ w2,
    const float* __restrict__ b2, float* __restrict__ out3)
{
    __shared__ float xr[2048];
    int sg0 = blockIdx.x * 4;
    int tid = threadIdx.x;
    for (int i = tid; i < 2048; i += 256) xr[i] = out2[(long)sg0 * 512 + i];
    __syncthreads();

    int sl = tid >> 6, d = tid & 63;
    float acc = 0.f;
    const float* xp = &xr[sl * 512];
    #pragma unroll 8
    for (int j = 0; j < 512; j++) acc += xp[j] * w1T[j * 64 + d];
    float hval = fmaxf(acc + b1[d], 0.f);
    float p = hval * w2[d];
    #pragma unroll
    for (int off = 32; off > 0; off >>= 1) p += __shfl_xor(p, off, 64);
    if (d == 0) out3[sg0 + sl] = p + b2[0];
}

// ---------------- launcher ----------------
extern "C" void kernel_launch(void* const* d_in, const int* in_sizes, int n_in,
                              void* d_out, int out_size, void* d_ws, size_t ws_size,
                              hipStream_t stream) {
    const float* x      = (const float*)d_in[0];
    const int*   length = (const int*)  d_in[1];
    const float* wq     = (const float*)d_in[2];
    const float* bq     = (const float*)d_in[3];
    const float* wk     = (const float*)d_in[4];
    const float* bk     = (const float*)d_in[5];
    const float* wv     = (const float*)d_in[6];
    const float* bv     = (const float*)d_in[7];
    const float* w1     = (const float*)d_in[8];
    const float* b1     = (const float*)d_in[9];
    const float* w2     = (const float*)d_in[10];
    const float* b2     = (const float*)d_in[11];

    float* out3  = (float*)d_out;
    float* score = (float*)d_out + 8192;   // (B,H,S,S) follows (B,S,1)

    float* ws  = (float*)d_ws;
    unsigned short* xh     = (unsigned short*)ws;  ws += 524288;
    unsigned short* wPackQ = (unsigned short*)ws;  ws += 98304;
    unsigned short* wPackK = (unsigned short*)ws;  ws += 98304;
    unsigned short* wPackV = (unsigned short*)ws;  ws += 32768;
    float* w1T = ws;  ws += 32768;
    unsigned short* Qh  = (unsigned short*)ws;  ws += 2097152;
    unsigned short* Kh  = (unsigned short*)ws;  ws += 2097152;
    unsigned short* VhT = (unsigned short*)ws;  ws += 2097152;
    float* o2  = ws;  ws += 4194304;

    hipLaunchKernelGGL(prep_kernel, dim3(6016), dim3(256), 0, stream,
                       x, wq, wk, wv, w1, xh, wPackQ, wPackK, wPackV, w1T);
    hipLaunchKernelGGL(qkv_kernel, dim3(16, 8, 4), dim3(256), 0, stream,
                       xh, wPackQ, wPackK, wPackV, bq, bk, bv, Qh, Kh, VhT);
    hipLaunchKernelGGL(attn_kernel, dim3(1024), dim3(256), 0, stream,
                       Qh, Kh, VhT, length, score, o2);
    hipLaunchKernelGGL(mlp_kernel, dim3(2048), dim3(256), 0, stream,
                       o2, w1T, b1, w2, b2, out3);
}